// Round 3
// baseline (375.585 us; speedup 1.0000x reference)
//
#include <hip/hip_runtime.h>
#include <math.h>

#define BATCH 8192
#define HDIM  1024
#define KDIM  2048

typedef __attribute__((ext_vector_type(8))) short short8;
typedef __attribute__((ext_vector_type(4))) float floatx4;

__device__ __forceinline__ float b2f(unsigned short u) {
  union { unsigned int i; float f; } v; v.i = ((unsigned int)u) << 16; return v.f;
}
__device__ __forceinline__ unsigned short f2b(float f) {
  union { unsigned int i; float f; } v; v.f = f;
  unsigned int r = v.i + 0x7FFFu + ((v.i >> 16) & 1u);
  return (unsigned short)(r >> 16);
}
__device__ __forceinline__ float ldsel(const void* p, size_t i, int isbf) {
  return isbf ? b2f(((const unsigned short*)p)[i]) : ((const float*)p)[i];
}
__device__ __forceinline__ float sigf(float x) { return 1.0f / (1.0f + __expf(-x)); }
__device__ __forceinline__ float tanhfast(float x) {
  float a = __builtin_fabsf(x);
  float t = __expf(-2.f * a);
  float r = (1.f - t) / (1.f + t);
  return copysignf(r, x);
}

// wave-uniform dtype detect from x[0..63]
__device__ __forceinline__ int detect_bf(const void* x) {
  unsigned int w = ((const unsigned int*)x)[threadIdx.x & 63];
  unsigned short lo = (unsigned short)(w & 0xFFFFu);
  int e = (lo >> 7) & 0xFF;
  bool ok = (e >= 110 && e <= 135) || ((lo & 0x7FFFu) == 0);
  unsigned long long m = __ballot(ok);
  return (__popcll(m) >= 48) ? 1 : 0;
}

// async 16B global->LDS
__device__ __forceinline__ void gld16(const void* g, void* l) {
  auto gp = reinterpret_cast<__attribute__((address_space(1))) unsigned int*>(
      (unsigned long long)g);
  auto lp = reinterpret_cast<__attribute__((address_space(3))) unsigned int*>(
      (unsigned long long)l);
  __builtin_amdgcn_global_load_lds(gp, lp, 16, 0, 0);
}

// load 8 bf16 (as short8) from either-format source at element offset
__device__ __forceinline__ short8 ld8bf(const void* p, size_t off, int isbf) {
  short8 r;
  if (isbf) {
    r = *(const short8*)((const unsigned short*)p + off);
  } else {
    const float* s = (const float*)p + off;
    float4 a = *(const float4*)(s);
    float4 b = *(const float4*)(s + 4);
    r[0]=(short)f2b(a.x); r[1]=(short)f2b(a.y); r[2]=(short)f2b(a.z); r[3]=(short)f2b(a.w);
    r[4]=(short)f2b(b.x); r[5]=(short)f2b(b.y); r[6]=(short)f2b(b.z); r[7]=(short)f2b(b.w);
  }
  return r;
}

// =============================================================== k_z2
// 512 blocks, 16 batch rows each, split-K over 4 waves. Also packs A (f32 path):
// the MFMA A-fragments it loads ARE the bf16 A-tile -> store them to A.
__global__ __launch_bounds__(256) void k_z2(
    const void* __restrict__ x, const void* __restrict__ h,
    const void* __restrict__ W1, const void* __restrict__ b1,
    const void* __restrict__ W2, const void* __restrict__ b2,
    unsigned short* __restrict__ A, float* __restrict__ z2) {
  __shared__ __align__(16) char smem[70976];
  const int isbf = detect_bf(x);
  const int tid = threadIdx.x;
  unsigned short* lW = (unsigned short*)smem;          // [16][2048] swizzled
  float* part = (float*)(smem + 65536);                // [4][16][17]
  float* z1s  = (float*)(smem + 69888);                // [16][17]
  const int m0 = blockIdx.x * 16;
  // stage W1 transposed into LDS: lW(row,k) at row*2048 + ((k>>3)^(row&7))*8 + (k&7)
#pragma unroll
  for (int it = 0; it < 16; ++it) {
    const int chunk = it * 256 + tid;   // 4096 chunks
    const int k = chunk >> 1;
    const int jh = (chunk & 1) * 8;
    unsigned short v[8];
    if (isbf) {
      short8 s = *(const short8*)((const unsigned short*)W1 + (size_t)k * 16 + jh);
#pragma unroll
      for (int j = 0; j < 8; ++j) v[j] = (unsigned short)s[j];
    } else {
      const float* s = (const float*)W1 + (size_t)k * 16 + jh;
      float4 a = *(const float4*)(s);
      float4 b = *(const float4*)(s + 4);
      v[0]=f2b(a.x); v[1]=f2b(a.y); v[2]=f2b(a.z); v[3]=f2b(a.w);
      v[4]=f2b(b.x); v[5]=f2b(b.y); v[6]=f2b(b.z); v[7]=f2b(b.w);
    }
#pragma unroll
    for (int j = 0; j < 8; ++j) {
      const int row = jh + j;
      lW[row * 2048 + (((k >> 3) ^ (row & 7)) << 3) + (k & 7)] = v[j];
    }
  }
  __syncthreads();
  const int w = tid >> 6;
  const int lane = tid & 63;
  const int q = lane >> 4;
  const int r = lane & 15;
  const void* src = (w >> 1) ? h : x;
  const size_t abase = (size_t)(m0 + r) * 1024 + (w & 1) * 512;
  const int kb = (w >> 1) * 1024 + (w & 1) * 512;   // global k base for B
  floatx4 acc = {0.f, 0.f, 0.f, 0.f};
#pragma unroll 4
  for (int kt = 0; kt < 16; ++kt) {
    const int kl = kt * 32 + q * 8;
    short8 a = ld8bf(src, abase + kl, isbf);
    const int kg = kb + kl;
    if (!isbf) *(short8*)(A + (size_t)(m0 + r) * KDIM + kg) = a;
    short8 b = *(const short8*)(lW + r * 2048 + (((kg >> 3) ^ (r & 7)) << 3));
    acc = __builtin_amdgcn_mfma_f32_16x16x32_bf16(a, b, acc, 0, 0, 0);
  }
#pragma unroll
  for (int t = 0; t < 4; ++t) part[(w * 16 + q * 4 + t) * 17 + r] = acc[t];
  __syncthreads();
  {
    const int row = tid >> 4;
    const int n = tid & 15;
    float s = part[(0 * 16 + row) * 17 + n] + part[(1 * 16 + row) * 17 + n] +
              part[(2 * 16 + row) * 17 + n] + part[(3 * 16 + row) * 17 + n] +
              ldsel(b1, (size_t)n, isbf);
    z1s[row * 17 + n] = fmaxf(s, 0.f);
  }
  __syncthreads();
  if (tid < 128) {
    const int row = tid >> 3;
    const int p = tid & 7;
    float s = ldsel(b2, (size_t)p, isbf);
#pragma unroll
    for (int nn = 0; nn < 16; ++nn)
      s += z1s[row * 17 + nn] * ldsel(W2, (size_t)nn * 8 + p, isbf);
    z2[(size_t)(m0 + row) * 8 + p] = fmaxf(s, 0.f);
  }
}

// =============================================================== k_wt
// 1536 blocks: WT pack, WT[n][k], n = gate*1024+hid. LDS 16640 B.
__global__ __launch_bounds__(256) void k_wt(
    const void* __restrict__ x,
    const void* __restrict__ wxi, const void* __restrict__ whi,
    const void* __restrict__ wxc, const void* __restrict__ whc,
    const void* __restrict__ wxo, const void* __restrict__ who,
    unsigned short* __restrict__ WT) {
  __shared__ __align__(16) float tbuf[64][65];
  const int isbf = detect_bf(x);
  const int tid = threadIdx.x;
  const int b = blockIdx.x;
  const int mat = b >> 8;
  const int rem = b & 255;
  const int ti = rem >> 4;
  const int tj = rem & 15;
  const void* Ws[6] = {wxi, whi, wxc, whc, wxo, who};
  const void* W = Ws[mat];
  const int gt = mat >> 1;
  const int half = mat & 1;
  const int rrow = tid >> 3;
  const int c8 = (tid & 7) * 8;
#pragma unroll
  for (int it = 0; it < 2; ++it) {
    int row = it * 32 + rrow;
    size_t off = (size_t)(ti * 64 + row) * 1024 + tj * 64 + c8;
    if (isbf) {
      const unsigned short* s = (const unsigned short*)W + off;
      ushort4 a = *(const ushort4*)(s);
      ushort4 bv = *(const ushort4*)(s + 4);
      tbuf[row][c8+0]=b2f(a.x);  tbuf[row][c8+1]=b2f(a.y);
      tbuf[row][c8+2]=b2f(a.z);  tbuf[row][c8+3]=b2f(a.w);
      tbuf[row][c8+4]=b2f(bv.x); tbuf[row][c8+5]=b2f(bv.y);
      tbuf[row][c8+6]=b2f(bv.z); tbuf[row][c8+7]=b2f(bv.w);
    } else {
      const float* s = (const float*)W + off;
      float4 a = *(const float4*)(s);
      float4 bv = *(const float4*)(s + 4);
      tbuf[row][c8+0]=a.x;  tbuf[row][c8+1]=a.y;  tbuf[row][c8+2]=a.z;  tbuf[row][c8+3]=a.w;
      tbuf[row][c8+4]=bv.x; tbuf[row][c8+5]=bv.y; tbuf[row][c8+6]=bv.z; tbuf[row][c8+7]=bv.w;
    }
  }
  __syncthreads();
#pragma unroll
  for (int it = 0; it < 2; ++it) {
    int nl = it * 32 + rrow;
    int n = gt * 1024 + tj * 64 + nl;
    int kk = half * 1024 + ti * 64 + c8;
    short8 pk;
#pragma unroll
    for (int i = 0; i < 8; ++i) pk[i] = (short)f2b(tbuf[c8 + i][nl]);
    *(short8*)(WT + (size_t)n * KDIM + kk) = pk;
  }
}

// =============================================================== k_gemm_f
// Fused GEMM + LSTM epilogue. 1024 blocks: 64 m-tiles(128) x 16 n-tiles(64 hid).
// Each block computes gates i,c,o for its tile (3 WT panels per k-step) and
// applies the LSTM pointwise math directly. No P round-trip.
__global__ __launch_bounds__(256) void k_gemm_f(
    const void* __restrict__ x, const void* __restrict__ h,
    const unsigned short* __restrict__ Apack,
    const unsigned short* __restrict__ WT,
    const void* __restrict__ cin,
    const void* __restrict__ bi, const void* __restrict__ bc,
    const void* __restrict__ bo,
    const float* __restrict__ z2,
    const void* __restrict__ W3, const void* __restrict__ b3,
    void* __restrict__ out) {
  const int isbf = detect_bf(x);
  const unsigned short* Ax = isbf ? (const unsigned short*)x : Apack;
  const unsigned short* Ah = isbf ? (const unsigned short*)h : (Apack + 1024);
  const int sA = isbf ? 1024 : KDIM;
  // LDS: lA[128][64] (16KB) + lB[3][64][64] (24KB)
  __shared__ __align__(16) char smem[40960];
  unsigned short* lA = (unsigned short*)smem;
  unsigned short* lB = (unsigned short*)(smem + 16384);
  const int tid = threadIdx.x;
  const int lane = tid & 63;
  const int wv = tid >> 6;
  const int wm = (wv >> 1) << 6;   // 0 or 64
  const int wn = (wv & 1) << 5;    // 0 or 32

  // XCD-aware bijective swizzle: 1024 blocks = 8 XCDs x 128.
  // Each XCD chunk: 8 m-panels x all 16 n-tiles (A panel ~4MB = one L2).
  const int bid = blockIdx.x;
  const int swz = ((bid & 7) << 7) | (bid >> 3);
  const int m0 = (swz >> 4) << 7;   // m-tile * 128
  const int n0 = (swz & 15) << 6;   // n-tile * 64

  floatx4 acc[3][4][2];
  const floatx4 fzero = {0.f, 0.f, 0.f, 0.f};
#pragma unroll
  for (int g = 0; g < 3; ++g)
#pragma unroll
    for (int i = 0; i < 4; ++i)
#pragma unroll
      for (int j = 0; j < 2; ++j) acc[g][i][j] = fzero;

  // staging assignments
  int rrA[4], kkA[4];
#pragma unroll
  for (int ps = 0; ps < 4; ++ps) {
    int c = ps * 256 + tid;            // 1024 chunks of 16B
    rrA[ps] = c >> 3;
    kkA[ps] = (c & 7) ^ (rrA[ps] & 7);
  }
  int gB[6], rrB[6], kkB[6];
#pragma unroll
  for (int ps = 0; ps < 6; ++ps) {
    int c = ps * 256 + tid;            // 1536 chunks of 16B
    gB[ps] = c >> 9;
    int cl = c & 511;
    rrB[ps] = cl >> 3;
    kkB[ps] = (cl & 7) ^ (rrB[ps] & 7);
  }
  const int px0 = (lane >> 4) ^ (lane & 7);
  const int px1 = ((lane >> 4) + 4) ^ (lane & 7);
  const int rowA = wm + (lane & 15);
  const int rowB = wn + (lane & 15);

  for (int kt = 0; kt < KDIM / 64; ++kt) {
    const int k0 = kt * 64;
    const unsigned short* Abase = (k0 < 1024) ? (Ax + k0) : (Ah + (k0 - 1024));
#pragma unroll
    for (int ps = 0; ps < 4; ++ps) {
      const int c = ps * 256 + tid;
      gld16(Abase + (size_t)(m0 + rrA[ps]) * sA + kkA[ps] * 8, lA + c * 8);
    }
#pragma unroll
    for (int ps = 0; ps < 6; ++ps) {
      const int c = ps * 256 + tid;
      gld16(WT + ((size_t)(gB[ps] * 1024 + n0 + rrB[ps]) * KDIM + k0 + kkB[ps] * 8),
            lB + c * 8);
    }
    __syncthreads();
#pragma unroll
    for (int s = 0; s < 2; ++s) {
      const int px = s ? px1 : px0;
      short8 af[4], bfr[3][2];
#pragma unroll
      for (int i = 0; i < 4; ++i)
        af[i] = *(const short8*)(lA + ((((rowA + (i << 4)) << 3) + px) << 3));
#pragma unroll
      for (int g = 0; g < 3; ++g)
#pragma unroll
        for (int j = 0; j < 2; ++j)
          bfr[g][j] = *(const short8*)(lB + (g << 12) +
                                       ((((rowB + (j << 4)) << 3) + px) << 3));
#pragma unroll
      for (int g = 0; g < 3; ++g)
#pragma unroll
        for (int mi = 0; mi < 4; ++mi)
#pragma unroll
          for (int ni = 0; ni < 2; ++ni)
            acc[g][mi][ni] = __builtin_amdgcn_mfma_f32_16x16x32_bf16(
                af[mi], bfr[g][ni], acc[g][mi][ni], 0, 0, 0);
    }
    __syncthreads();
  }

  // ---- epilogue: stage z2 rows for this m-panel into LDS (reuse lA space)
  float* z2s = (float*)smem;   // [128][8] f32 = 4KB
  *(float4*)(z2s + tid * 4) = *(const float4*)(z2 + (size_t)m0 * 8 + tid * 4);
  __syncthreads();

  const int col_l = lane & 15;
  const int rq = (lane >> 4) << 2;
  // hoist per-column constants (2 columns per lane)
  float w3c[2][8], b3c[2], bic[2], bcc[2], boc[2];
#pragma unroll
  for (int ni = 0; ni < 2; ++ni) {
    const size_t n_g = (size_t)(n0 + wn + (ni << 4) + col_l);
    b3c[ni] = ldsel(b3, n_g, isbf);
    bic[ni] = ldsel(bi, n_g, isbf);
    bcc[ni] = ldsel(bc, n_g, isbf);
    boc[ni] = ldsel(bo, n_g, isbf);
#pragma unroll
    for (int j = 0; j < 8; ++j) w3c[ni][j] = ldsel(W3, (size_t)j * 1024 + n_g, isbf);
  }
  const size_t MH = (size_t)BATCH * HDIM;
#pragma unroll
  for (int mi = 0; mi < 4; ++mi) {
#pragma unroll
    for (int t = 0; t < 4; ++t) {
      const int rloc = wm + (mi << 4) + rq + t;      // block-local row
      const size_t m_g = (size_t)m0 + rloc;
      float zz[8];
#pragma unroll
      for (int j = 0; j < 8; ++j) zz[j] = z2s[rloc * 8 + j];
#pragma unroll
      for (int ni = 0; ni < 2; ++ni) {
        const size_t n_g = (size_t)(n0 + wn + (ni << 4) + col_l);
        const size_t idx = m_g * HDIM + n_g;
        float f3 = b3c[ni];
#pragma unroll
        for (int j = 0; j < 8; ++j) f3 += zz[j] * w3c[ni][j];
        const float cf = isbf ? b2f(((const unsigned short*)cin)[idx])
                              : ((const float*)cin)[idx];
        const float F = sigf(f3);
        const float I = sigf(acc[0][mi][ni][t] + bic[ni]);
        const float G = tanhfast(acc[1][mi][ni][t] + bcc[ni]);
        const float O = sigf(acc[2][mi][ni][t] + boc[ni]);
        const float C = F * cf + I * G;
        const float HN = O * tanhfast(C);
        if (isbf) {
          unsigned short* ob = (unsigned short*)out;
          ob[idx] = f2b(HN);
          ob[MH + idx] = f2b(C);
          ob[2 * MH + idx] = f2b(F);
        } else {
          float* ob = (float*)out;
          ob[idx] = HN;
          ob[MH + idx] = C;
          ob[2 * MH + idx] = F;
        }
      }
    }
  }
}

extern "C" void kernel_launch(void* const* d_in, const int* in_sizes, int n_in,
                              void* d_out, int out_size, void* d_ws, size_t ws_size,
                              hipStream_t stream) {
  const void* x    = d_in[0];
  const void* h    = d_in[1];
  const void* c    = d_in[2];
  const void* W_hi = d_in[3];
  const void* W_xi = d_in[4];
  const void* b_i  = d_in[5];
  const void* W_hc = d_in[6];
  const void* W_xc = d_in[7];
  const void* b_c  = d_in[8];
  const void* W_ho = d_in[9];
  const void* W_xo = d_in[10];
  const void* b_o  = d_in[11];
  const void* W1   = d_in[12];
  const void* b1   = d_in[13];
  const void* W2   = d_in[14];
  const void* b2   = d_in[15];
  const void* W3   = d_in[16];
  const void* b3   = d_in[17];

  char* ws = (char*)d_ws;
  unsigned short* A   = (unsigned short*)ws;                 // 33.5 MB (f32 path)
  unsigned short* WT  = (unsigned short*)(ws + 33554432);    // 12.6 MB
  float*          z2b = (float*)(ws + 96468992);             // 256 KB

  k_z2<<<dim3(512), dim3(256), 0, stream>>>(x, h, W1, b1, W2, b2, A, z2b);
  k_wt<<<dim3(1536), dim3(256), 0, stream>>>(x, W_xi, W_hi, W_xc, W_hc,
                                             W_xo, W_ho, WT);
  k_gemm_f<<<dim3(1024), dim3(256), 0, stream>>>(x, h, A, WT, c, b_i, b_c, b_o,
                                                 z2b, W3, b3, d_out);
}

// Round 4
// 351.172 us; speedup vs baseline: 1.0695x; 1.0695x over previous
//
#include <hip/hip_runtime.h>
#include <math.h>

#define BATCH 8192
#define HDIM  1024
#define KDIM  2048
#define NDIM  3072

typedef __attribute__((ext_vector_type(8))) short short8;
typedef __attribute__((ext_vector_type(4))) float floatx4;

__device__ __forceinline__ float b2f(unsigned short u) {
  union { unsigned int i; float f; } v; v.i = ((unsigned int)u) << 16; return v.f;
}
__device__ __forceinline__ unsigned short f2b(float f) {
  union { unsigned int i; float f; } v; v.f = f;
  unsigned int r = v.i + 0x7FFFu + ((v.i >> 16) & 1u);
  return (unsigned short)(r >> 16);
}
__device__ __forceinline__ float ldsel(const void* p, size_t i, int isbf) {
  return isbf ? b2f(((const unsigned short*)p)[i]) : ((const float*)p)[i];
}
__device__ __forceinline__ float sigf(float x) { return 1.0f / (1.0f + __expf(-x)); }
__device__ __forceinline__ float tanhfast(float x) {
  float a = __builtin_fabsf(x);
  float t = __expf(-2.f * a);
  float r = (1.f - t) / (1.f + t);
  return copysignf(r, x);
}

// wave-uniform dtype detect from x[0..63]
__device__ __forceinline__ int detect_bf(const void* x) {
  unsigned int w = ((const unsigned int*)x)[threadIdx.x & 63];
  unsigned short lo = (unsigned short)(w & 0xFFFFu);
  int e = (lo >> 7) & 0xFF;
  bool ok = (e >= 110 && e <= 135) || ((lo & 0x7FFFu) == 0);
  unsigned long long m = __ballot(ok);
  return (__popcll(m) >= 48) ? 1 : 0;
}

// async 16B global->LDS
__device__ __forceinline__ void gld16(const void* g, void* l) {
  auto gp = reinterpret_cast<__attribute__((address_space(1))) unsigned int*>(
      (unsigned long long)g);
  auto lp = reinterpret_cast<__attribute__((address_space(3))) unsigned int*>(
      (unsigned long long)l);
  __builtin_amdgcn_global_load_lds(gp, lp, 16, 0, 0);
}

// load 8 bf16 (as short8) from either-format source at element offset
__device__ __forceinline__ short8 ld8bf(const void* p, size_t off, int isbf) {
  short8 r;
  if (isbf) {
    r = *(const short8*)((const unsigned short*)p + off);
  } else {
    const float* s = (const float*)p + off;
    float4 a = *(const float4*)(s);
    float4 b = *(const float4*)(s + 4);
    r[0]=(short)f2b(a.x); r[1]=(short)f2b(a.y); r[2]=(short)f2b(a.z); r[3]=(short)f2b(a.w);
    r[4]=(short)f2b(b.x); r[5]=(short)f2b(b.y); r[6]=(short)f2b(b.z); r[7]=(short)f2b(b.w);
  }
  return r;
}

// =============================================================== k_prep
// Replaces k_z2 + k_apack. 512 blocks x 16 rows. All global access coalesced:
// each thread reads 64 contiguous bytes of one row, converts once, writes A
// coalesced, and stages an XOR-swizzled LDS tile for the z1 MFMA.
__global__ __launch_bounds__(256) void k_prep(
    const void* __restrict__ x, const void* __restrict__ h,
    const void* __restrict__ W1, const void* __restrict__ b1,
    const void* __restrict__ W2, const void* __restrict__ b2,
    unsigned short* __restrict__ A, float* __restrict__ z2) {
  __shared__ __align__(16) unsigned short tA[16 * 256];  // 8 KB, row-major swz
  __shared__ __align__(16) unsigned short tB[16 * 256];  // 8 KB, col-major swz (W1^T)
  __shared__ float part[4 * 16 * 17];                    // 4.35 KB
  __shared__ float z1s[16 * 17];                         // 1.1 KB
  const int isbf = detect_bf(x);
  const int tid = threadIdx.x;
  const int m0 = blockIdx.x * 16;
  const int lane = tid & 63;
  const int w = tid >> 6;
  const int q = lane >> 4;
  const int r = lane & 15;
  char* tAb = (char*)tA;
  char* tBb = (char*)tB;

  const int arow = tid >> 4;          // 0..15
  const int ak = (tid & 15) * 16;     // 0..240, 16 elems per thread

  floatx4 acc = {0.f, 0.f, 0.f, 0.f};

  for (int ktile = 0; ktile < 8; ++ktile) {
    const int k0 = ktile * 256;
    const void* src = (k0 < 1024) ? x : h;
    const int klocal = (k0 & 1023) + ak;
    // ---- coalesced row loads (64B/thread) + convert
    short8 v0 = ld8bf(src, (size_t)(m0 + arow) * 1024 + klocal, isbf);
    short8 v1 = ld8bf(src, (size_t)(m0 + arow) * 1024 + klocal + 8, isbf);
    // ---- coalesced W1 tile load: thread t reads W1[k0+t][0..16]
    float wv[16];
    if (isbf) {
      const unsigned short* s = (const unsigned short*)W1 + (size_t)(k0 + tid) * 16;
      short8 s0 = *(const short8*)(s);
      short8 s1 = *(const short8*)(s + 8);
#pragma unroll
      for (int j = 0; j < 8; ++j) { wv[j] = b2f((unsigned short)s0[j]);
                                    wv[8 + j] = b2f((unsigned short)s1[j]); }
    } else {
      const float* s = (const float*)W1 + (size_t)(k0 + tid) * 16;
      float4 a0 = *(const float4*)(s);
      float4 a1 = *(const float4*)(s + 4);
      float4 a2 = *(const float4*)(s + 8);
      float4 a3 = *(const float4*)(s + 12);
      wv[0]=a0.x; wv[1]=a0.y; wv[2]=a0.z; wv[3]=a0.w;
      wv[4]=a1.x; wv[5]=a1.y; wv[6]=a1.z; wv[7]=a1.w;
      wv[8]=a2.x; wv[9]=a2.y; wv[10]=a2.z; wv[11]=a2.w;
      wv[12]=a3.x; wv[13]=a3.y; wv[14]=a3.z; wv[15]=a3.w;
    }
    // ---- coalesced A-pack store (f32 path only)
    if (!isbf) {
      unsigned short* Ao = A + (size_t)(m0 + arow) * KDIM + k0 + ak;
      *(short8*)(Ao) = v0;
      *(short8*)(Ao + 8) = v1;
    }
    // ---- LDS stage, XOR-swizzled (bit4 ^ row low bits) for conflict-free b128
    {
      const int base = arow * 512 + ak * 2;
      const int sw = (arow & 7) << 4;
      *(short8*)(tAb + ((base) ^ sw)) = v0;
      *(short8*)(tAb + ((base + 16) ^ sw)) = v1;
    }
#pragma unroll
    for (int j = 0; j < 16; ++j) {
      // col-major W1^T: [col j][k=tid], consecutive lanes -> consecutive 2B
      *(unsigned short*)(tBb + ((j * 512 + tid * 2) ^ ((j & 7) << 4))) = f2b(wv[j]);
    }
    __syncthreads();
    // ---- MFMA: wave w covers k-subtiles {2w, 2w+1} of this tile
#pragma unroll
    for (int s = 0; s < 2; ++s) {
      const int ks = (w * 2 + s) * 32 + q * 8;   // k within tile
      short8 af = *(const short8*)(tAb + ((r * 512 + ks * 2) ^ ((r & 7) << 4)));
      short8 bf = *(const short8*)(tBb + ((r * 512 + ks * 2) ^ ((r & 7) << 4)));
      acc = __builtin_amdgcn_mfma_f32_16x16x32_bf16(af, bf, acc, 0, 0, 0);
    }
    __syncthreads();
  }
  // ---- reduce 4 wave-partials, bias+relu, z2 = relu(z1*W2+b2)
#pragma unroll
  for (int t = 0; t < 4; ++t) part[(w * 16 + q * 4 + t) * 17 + r] = acc[t];
  __syncthreads();
  {
    const int row = tid >> 4;
    const int n = tid & 15;
    float s = part[(0 * 16 + row) * 17 + n] + part[(1 * 16 + row) * 17 + n] +
              part[(2 * 16 + row) * 17 + n] + part[(3 * 16 + row) * 17 + n] +
              ldsel(b1, (size_t)n, isbf);
    z1s[row * 17 + n] = fmaxf(s, 0.f);
  }
  __syncthreads();
  if (tid < 128) {
    const int row = tid >> 3;
    const int p = tid & 7;
    float s = ldsel(b2, (size_t)p, isbf);
#pragma unroll
    for (int nn = 0; nn < 16; ++nn)
      s += z1s[row * 17 + nn] * ldsel(W2, (size_t)nn * 8 + p, isbf);
    z2[(size_t)(m0 + row) * 8 + p] = fmaxf(s, 0.f);
  }
}

// =============================================================== k_wt
// 1536 blocks: WT pack, WT[n][k], n = gate*1024+hid. LDS 16640 B.
__global__ __launch_bounds__(256) void k_wt(
    const void* __restrict__ x,
    const void* __restrict__ wxi, const void* __restrict__ whi,
    const void* __restrict__ wxc, const void* __restrict__ whc,
    const void* __restrict__ wxo, const void* __restrict__ who,
    unsigned short* __restrict__ WT) {
  __shared__ __align__(16) float tbuf[64][65];
  const int isbf = detect_bf(x);
  const int tid = threadIdx.x;
  const int b = blockIdx.x;
  const int mat = b >> 8;
  const int rem = b & 255;
  const int ti = rem >> 4;
  const int tj = rem & 15;
  const void* Ws[6] = {wxi, whi, wxc, whc, wxo, who};
  const void* W = Ws[mat];
  const int gt = mat >> 1;
  const int half = mat & 1;
  const int rrow = tid >> 3;
  const int c8 = (tid & 7) * 8;
#pragma unroll
  for (int it = 0; it < 2; ++it) {
    int row = it * 32 + rrow;
    size_t off = (size_t)(ti * 64 + row) * 1024 + tj * 64 + c8;
    if (isbf) {
      const unsigned short* s = (const unsigned short*)W + off;
      ushort4 a = *(const ushort4*)(s);
      ushort4 bv = *(const ushort4*)(s + 4);
      tbuf[row][c8+0]=b2f(a.x);  tbuf[row][c8+1]=b2f(a.y);
      tbuf[row][c8+2]=b2f(a.z);  tbuf[row][c8+3]=b2f(a.w);
      tbuf[row][c8+4]=b2f(bv.x); tbuf[row][c8+5]=b2f(bv.y);
      tbuf[row][c8+6]=b2f(bv.z); tbuf[row][c8+7]=b2f(bv.w);
    } else {
      const float* s = (const float*)W + off;
      float4 a = *(const float4*)(s);
      float4 bv = *(const float4*)(s + 4);
      tbuf[row][c8+0]=a.x;  tbuf[row][c8+1]=a.y;  tbuf[row][c8+2]=a.z;  tbuf[row][c8+3]=a.w;
      tbuf[row][c8+4]=bv.x; tbuf[row][c8+5]=bv.y; tbuf[row][c8+6]=bv.z; tbuf[row][c8+7]=bv.w;
    }
  }
  __syncthreads();
#pragma unroll
  for (int it = 0; it < 2; ++it) {
    int nl = it * 32 + rrow;
    int n = gt * 1024 + tj * 64 + nl;
    int kk = half * 1024 + ti * 64 + c8;
    short8 pk;
#pragma unroll
    for (int i = 0; i < 8; ++i) pk[i] = (short)f2b(tbuf[c8 + i][nl]);
    *(short8*)(WT + (size_t)n * KDIM + kk) = pk;
  }
}

// =============================================================== k_gemm (proven R2)
__global__ __launch_bounds__(256, 3) void k_gemm(
    const void* __restrict__ x, const void* __restrict__ h,
    const unsigned short* __restrict__ Apack,
    const unsigned short* __restrict__ WT,
    unsigned short* __restrict__ P) {
  const int isbf = detect_bf(x);
  const unsigned short* Ax = isbf ? (const unsigned short*)x : Apack;
  const unsigned short* Ah = isbf ? (const unsigned short*)h : (Apack + 1024);
  const int sA = isbf ? 1024 : 2048;
  __shared__ __align__(16) unsigned short lA[128 * 64];
  __shared__ __align__(16) unsigned short lB[128 * 64];
  const int tid = threadIdx.x;
  const int lane = tid & 63;
  const int wv = tid >> 6;
  const int wm = (wv >> 1) << 6;
  const int wn = (wv & 1) << 6;
  const int m0 = blockIdx.y << 7;
  const int n0 = blockIdx.x << 7;

  floatx4 acc[4][4];
  const floatx4 fzero = {0.f, 0.f, 0.f, 0.f};
#pragma unroll
  for (int i = 0; i < 4; ++i)
#pragma unroll
    for (int j = 0; j < 4; ++j) acc[i][j] = fzero;

  int rr[4], kk[4];
#pragma unroll
  for (int ps = 0; ps < 4; ++ps) {
    int chunk = ps * 256 + tid;
    rr[ps] = chunk >> 3;
    kk[ps] = (chunk & 7) ^ (rr[ps] & 7);
  }
  const int px0 = (lane >> 4) ^ (lane & 7);
  const int px1 = ((lane >> 4) + 4) ^ (lane & 7);
  const int rowA = wm + (lane & 15);
  const int rowB = wn + (lane & 15);

  for (int kt = 0; kt < KDIM / 64; ++kt) {
    const int k0 = kt * 64;
    const unsigned short* Abase = (k0 < 1024) ? (Ax + k0) : (Ah + (k0 - 1024));
#pragma unroll
    for (int ps = 0; ps < 4; ++ps) {
      const int chunk = ps * 256 + tid;
      gld16(Abase + (size_t)(m0 + rr[ps]) * sA + kk[ps] * 8, lA + chunk * 8);
      gld16(WT + ((size_t)(n0 + rr[ps]) * KDIM + k0 + kk[ps] * 8), lB + chunk * 8);
    }
    __syncthreads();
#pragma unroll
    for (int s = 0; s < 2; ++s) {
      const int px = s ? px1 : px0;
      short8 af[4], bfr[4];
#pragma unroll
      for (int i = 0; i < 4; ++i)
        af[i] = *(const short8*)(lA + ((((rowA + (i << 4)) << 3) + px) << 3));
#pragma unroll
      for (int i = 0; i < 4; ++i)
        bfr[i] = *(const short8*)(lB + ((((rowB + (i << 4)) << 3) + px) << 3));
#pragma unroll
      for (int mi = 0; mi < 4; ++mi)
#pragma unroll
        for (int ni = 0; ni < 4; ++ni)
          acc[mi][ni] = __builtin_amdgcn_mfma_f32_16x16x32_bf16(
              af[mi], bfr[ni], acc[mi][ni], 0, 0, 0);
    }
    __syncthreads();
  }
  const int col = lane & 15;
  const int rq = (lane >> 4) << 2;
#pragma unroll
  for (int mi = 0; mi < 4; ++mi) {
#pragma unroll
    for (int ni = 0; ni < 4; ++ni) {
      const size_t n = (size_t)(n0 + wn + (ni << 4) + col);
#pragma unroll
      for (int t = 0; t < 4; ++t) {
        const size_t m = (size_t)(m0 + wm + (mi << 4) + rq + t);
        P[m * NDIM + n] = f2b(acc[mi][ni][t]);
      }
    }
  }
}

// =============================================================== k_pointwise
// 1024 blocks x 8 batch rows. W3 slice in registers (no LDS, no barrier).
__global__ __launch_bounds__(256) void k_pointwise(
    const unsigned short* __restrict__ P, const void* __restrict__ x,
    const void* __restrict__ cin,
    const void* __restrict__ bi, const void* __restrict__ bc,
    const void* __restrict__ bo, const float* __restrict__ z2,
    const void* __restrict__ W3, const void* __restrict__ b3,
    void* __restrict__ out) {
  const int isbf = detect_bf(x);
  const int tid = threadIdx.x;
  const int n = tid * 4;
  const size_t MH = (size_t)BATCH * HDIM;

  float w3r[8][4], bif[4], bcf[4], bof[4], b3f[4];
  if (isbf) {
#pragma unroll
    for (int j = 0; j < 8; ++j) {
      ushort4 u = *(const ushort4*)((const unsigned short*)W3 + j * 1024 + n);
      w3r[j][0]=b2f(u.x); w3r[j][1]=b2f(u.y); w3r[j][2]=b2f(u.z); w3r[j][3]=b2f(u.w);
    }
    ushort4 u3 = *(const ushort4*)((const unsigned short*)b3 + n);
    b3f[0]=b2f(u3.x); b3f[1]=b2f(u3.y); b3f[2]=b2f(u3.z); b3f[3]=b2f(u3.w);
    ushort4 a = *(const ushort4*)((const unsigned short*)bi + n);
    ushort4 b = *(const ushort4*)((const unsigned short*)bc + n);
    ushort4 d = *(const ushort4*)((const unsigned short*)bo + n);
    bif[0]=b2f(a.x); bif[1]=b2f(a.y); bif[2]=b2f(a.z); bif[3]=b2f(a.w);
    bcf[0]=b2f(b.x); bcf[1]=b2f(b.y); bcf[2]=b2f(b.z); bcf[3]=b2f(b.w);
    bof[0]=b2f(d.x); bof[1]=b2f(d.y); bof[2]=b2f(d.z); bof[3]=b2f(d.w);
  } else {
#pragma unroll
    for (int j = 0; j < 8; ++j) {
      float4 u = *(const float4*)((const float*)W3 + j * 1024 + n);
      w3r[j][0]=u.x; w3r[j][1]=u.y; w3r[j][2]=u.z; w3r[j][3]=u.w;
    }
    float4 u3 = *(const float4*)((const float*)b3 + n);
    b3f[0]=u3.x; b3f[1]=u3.y; b3f[2]=u3.z; b3f[3]=u3.w;
    float4 a = *(const float4*)((const float*)bi + n);
    float4 b = *(const float4*)((const float*)bc + n);
    float4 d = *(const float4*)((const float*)bo + n);
    bif[0]=a.x; bif[1]=a.y; bif[2]=a.z; bif[3]=a.w;
    bcf[0]=b.x; bcf[1]=b.y; bcf[2]=b.z; bcf[3]=b.w;
    bof[0]=d.x; bof[1]=d.y; bof[2]=d.z; bof[3]=d.w;
  }

  const size_t m0 = (size_t)blockIdx.x * 8;
#pragma unroll
  for (int rI = 0; rI < 8; ++rI) {
    const size_t m = m0 + rI;
    const size_t idx = m * 1024 + n;
    const unsigned short* pr = P + m * NDIM + n;
    ushort4 ui = *(const ushort4*)(pr);
    ushort4 ug = *(const ushort4*)(pr + 1024);
    ushort4 uo = *(const ushort4*)(pr + 2048);
    float pi[4] = {b2f(ui.x), b2f(ui.y), b2f(ui.z), b2f(ui.w)};
    float pg[4] = {b2f(ug.x), b2f(ug.y), b2f(ug.z), b2f(ug.w)};
    float po[4] = {b2f(uo.x), b2f(uo.y), b2f(uo.z), b2f(uo.w)};
    float4 za = *(const float4*)(z2 + m * 8);
    float4 zb = *(const float4*)(z2 + m * 8 + 4);
    float zz[8] = {za.x, za.y, za.z, za.w, zb.x, zb.y, zb.z, zb.w};
    float cf[4];
    if (isbf) {
      ushort4 e = *(const ushort4*)((const unsigned short*)cin + idx);
      cf[0]=b2f(e.x); cf[1]=b2f(e.y); cf[2]=b2f(e.z); cf[3]=b2f(e.w);
    } else {
      float4 e = *(const float4*)((const float*)cin + idx);
      cf[0]=e.x; cf[1]=e.y; cf[2]=e.z; cf[3]=e.w;
    }
    float f3[4] = {b3f[0], b3f[1], b3f[2], b3f[3]};
#pragma unroll
    for (int j = 0; j < 8; ++j) {
      f3[0] += zz[j] * w3r[j][0];
      f3[1] += zz[j] * w3r[j][1];
      f3[2] += zz[j] * w3r[j][2];
      f3[3] += zz[j] * w3r[j][3];
    }
    float hn[4], cn[4], ff[4];
#pragma unroll
    for (int t = 0; t < 4; ++t) {
      float F = sigf(f3[t]);
      float I = sigf(pi[t] + bif[t]);
      float G = tanhfast(pg[t] + bcf[t]);
      float O = sigf(po[t] + bof[t]);
      float C = F * cf[t] + I * G;
      ff[t] = F;
      cn[t] = C;
      hn[t] = O * tanhfast(C);
    }
    if (isbf) {
      unsigned short* ob = (unsigned short*)out;
      *(ushort4*)(ob + idx) = make_ushort4(f2b(hn[0]), f2b(hn[1]), f2b(hn[2]), f2b(hn[3]));
      *(ushort4*)(ob + MH + idx) = make_ushort4(f2b(cn[0]), f2b(cn[1]), f2b(cn[2]), f2b(cn[3]));
      *(ushort4*)(ob + 2 * MH + idx) = make_ushort4(f2b(ff[0]), f2b(ff[1]), f2b(ff[2]), f2b(ff[3]));
    } else {
      float* ob = (float*)out;
      *(float4*)(ob + idx) = make_float4(hn[0], hn[1], hn[2], hn[3]);
      *(float4*)(ob + MH + idx) = make_float4(cn[0], cn[1], cn[2], cn[3]);
      *(float4*)(ob + 2 * MH + idx) = make_float4(ff[0], ff[1], ff[2], ff[3]);
    }
  }
}

extern "C" void kernel_launch(void* const* d_in, const int* in_sizes, int n_in,
                              void* d_out, int out_size, void* d_ws, size_t ws_size,
                              hipStream_t stream) {
  const void* x    = d_in[0];
  const void* h    = d_in[1];
  const void* c    = d_in[2];
  const void* W_hi = d_in[3];
  const void* W_xi = d_in[4];
  const void* b_i  = d_in[5];
  const void* W_hc = d_in[6];
  const void* W_xc = d_in[7];
  const void* b_c  = d_in[8];
  const void* W_ho = d_in[9];
  const void* W_xo = d_in[10];
  const void* b_o  = d_in[11];
  const void* W1   = d_in[12];
  const void* b1   = d_in[13];
  const void* W2   = d_in[14];
  const void* b2   = d_in[15];
  const void* W3   = d_in[16];
  const void* b3   = d_in[17];

  char* ws = (char*)d_ws;
  unsigned short* A   = (unsigned short*)ws;                 // 33.5 MB (f32 path)
  unsigned short* WT  = (unsigned short*)(ws + 33554432);    // 12.6 MB
  unsigned short* P   = (unsigned short*)(ws + 46137344);    // 50.3 MB
  float*          z2b = (float*)(ws + 96468992);             // 256 KB

  k_prep<<<dim3(512), dim3(256), 0, stream>>>(x, h, W1, b1, W2, b2, A, z2b);
  k_wt<<<dim3(1536), dim3(256), 0, stream>>>(x, W_xi, W_hi, W_xc, W_hc,
                                             W_xo, W_ho, WT);
  k_gemm<<<dim3(NDIM / 128, BATCH / 128), dim3(256), 0, stream>>>(x, h, A, WT, P);
  k_pointwise<<<dim3(BATCH / 8), dim3(256), 0, stream>>>(P, x, c, b_i, b_c, b_o,
                                                         z2b, W3, b3, d_out);
}